// Round 1
// baseline (1060.309 us; speedup 1.0000x reference)
//
#include <hip/hip_runtime.h>

#define N_  64
#define CI  256
#define CO  256
#define CR  32
#define T_  64
#define V_  25
#define TV  (T_*V_)   // 1600
#define VV  (V_*V_)   // 625

// ---------------- K1: xm[n,c,v] = mean_t x[n,c,t,v] ----------------
__global__ __launch_bounds__(256) void k_mean(const float* __restrict__ x,
                                              float* __restrict__ xm) {
    int idx = blockIdx.x * 256 + threadIdx.x;           // over N*CI*V
    if (idx >= N_ * CI * V_) return;
    int v  = idx % V_;
    int nc = idx / V_;
    const float* p = x + (size_t)nc * TV + v;
    float s = 0.f;
    for (int t = 0; t < T_; ++t) s += p[t * V_];
    xm[idx] = s * (1.f / T_);
}

// ---------------- K2: x1/x2 = w1/w2 @ xm + b ----------------
__global__ __launch_bounds__(256) void k_x1x2(const float* __restrict__ xm,
                                              const float* __restrict__ w1,
                                              const float* __restrict__ b1,
                                              const float* __restrict__ w2,
                                              const float* __restrict__ b2,
                                              float* __restrict__ x1,
                                              float* __restrict__ x2) {
    int n = blockIdx.x;
    __shared__ float s_xm[CI * V_];
    const float4* src = (const float4*)(xm + (size_t)n * CI * V_);
    for (int i = threadIdx.x; i < CI * V_ / 4; i += 256) ((float4*)s_xm)[i] = src[i];
    __syncthreads();
    for (int idx = threadIdx.x; idx < CR * V_; idx += 256) {
        int r = idx / V_, v = idx % V_;
        float a1 = 0.f, a2 = 0.f;
        for (int c = 0; c < CI; ++c) {
            float xv = s_xm[c * V_ + v];
            a1 += w1[r * CI + c] * xv;
            a2 += w2[r * CI + c] * xv;
        }
        x1[n * CR * V_ + idx] = a1 + b1[r];
        x2[n * CR * V_ + idx] = a2 + b2[r];
    }
}

// ---------------- K3: attn[n,o,u,v] ----------------
// attn = (sum_r w4[o,r]*tanh(x1[n,r,u]-x2[n,r,v]) + b4[o]) * alpha + A[u,v]
#define AFF_S 33
__global__ __launch_bounds__(256) void k_attn(const float* __restrict__ x1,
                                              const float* __restrict__ x2,
                                              const float* __restrict__ w4,
                                              const float* __restrict__ b4,
                                              const float* __restrict__ A,
                                              const int* __restrict__ alpha_p,
                                              float* __restrict__ attn) {
    int n  = blockIdx.x;
    int o0 = blockIdx.y * 64;
    __shared__ float s_x1[CR * V_];
    __shared__ float s_x2[CR * V_];
    __shared__ float s_aff[VV * AFF_S];
    __shared__ float s_w4[64 * CR];
    __shared__ float s_A[VV];
    float alpha = (float)alpha_p[0];
    for (int i = threadIdx.x; i < CR * V_; i += 256) {
        s_x1[i] = x1[n * CR * V_ + i];
        s_x2[i] = x2[n * CR * V_ + i];
    }
    for (int i = threadIdx.x; i < 64 * CR; i += 256) s_w4[i] = w4[o0 * CR + i];
    for (int i = threadIdx.x; i < VV; i += 256) s_A[i] = A[i];
    __syncthreads();
    // aff[uv][r] = tanh(x1[r,u] - x2[r,v]), padded stride 33
    for (int i = threadIdx.x; i < VV * CR; i += 256) {
        int r = i % CR;
        int uv = i / CR;
        int u = uv / V_, v = uv % V_;
        s_aff[uv * AFF_S + r] = tanhf(s_x1[r * V_ + u] - s_x2[r * V_ + v]);
    }
    __syncthreads();
    for (int base = 0; base < VV; base += 256) {
        int uv = base + threadIdx.x;
        if (uv >= VV) break;
        float av[CR];
        #pragma unroll
        for (int r = 0; r < CR; ++r) av[r] = s_aff[uv * AFF_S + r];
        float Auv = s_A[uv];
        for (int oo = 0; oo < 64; ++oo) {
            float acc = b4[o0 + oo];
            #pragma unroll
            for (int r = 0; r < CR; ++r) acc += s_w4[oo * CR + r] * av[r];
            attn[((size_t)n * CO + o0 + oo) * VV + uv] = acc * alpha + Auv;
        }
    }
}

// ---------------- K4: fused x3-GEMM + graph contraction ----------------
// block = (n, o-tile of 32, t-tile of 32); thread: 4 o  x 1 t x 25 u accumulators
__global__ __launch_bounds__(256) void k_gemm_contract(const float* __restrict__ x,
                                                       const float* __restrict__ w3,
                                                       const float* __restrict__ b3,
                                                       const float* __restrict__ attn,
                                                       float* __restrict__ out) {
    int n  = blockIdx.x;
    int o0 = blockIdx.y * 32;
    int t0 = blockIdx.z * 32;
    __shared__ float smem[16 * 700];   // union: GEMM x-stage (6400 f) / attn half (11200 f)
    float* s_x = smem;
    int tloc = threadIdx.x & 31;
    int oo   = threadIdx.x >> 5;       // 0..7

    float acc[4][25];
    #pragma unroll
    for (int s = 0; s < 4; ++s)
        #pragma unroll
        for (int u = 0; u < 25; ++u) acc[s][u] = 0.f;

    const size_t xbase = (size_t)n * CI * TV + (size_t)t0 * V_;
    for (int ck = 0; ck < 32; ++ck) {
        const int c0 = ck * 8;
        __syncthreads();
        // stage x[n, c0..c0+7, t0..t0+31, :] -> s_x[cc][t][u], float4 coalesced
        for (int i = threadIdx.x; i < 1600; i += 256) {
            int cc = i / 200, r4 = i % 200;
            const float4* gp = (const float4*)(x + xbase + (size_t)(c0 + cc) * TV);
            ((float4*)s_x)[cc * 200 + r4] = gp[r4];
        }
        __syncthreads();
        float w[4][8];
        #pragma unroll
        for (int s = 0; s < 4; ++s) {
            const float* wp = w3 + (size_t)(o0 + oo + s * 8) * CI + c0;
            float4 wa = *(const float4*)wp;
            float4 wb = *(const float4*)(wp + 4);
            w[s][0] = wa.x; w[s][1] = wa.y; w[s][2] = wa.z; w[s][3] = wa.w;
            w[s][4] = wb.x; w[s][5] = wb.y; w[s][6] = wb.z; w[s][7] = wb.w;
        }
        #pragma unroll
        for (int cc = 0; cc < 8; ++cc) {
            float xv[25];
            #pragma unroll
            for (int u = 0; u < 25; ++u) xv[u] = s_x[cc * 800 + tloc * 25 + u];
            #pragma unroll
            for (int s = 0; s < 4; ++s)
                #pragma unroll
                for (int u = 0; u < 25; ++u) acc[s][u] += w[s][cc] * xv[u];
        }
    }
    // x3 = gemm + b3
    #pragma unroll
    for (int s = 0; s < 4; ++s) {
        float bv = b3[o0 + oo + s * 8];
        #pragma unroll
        for (int u = 0; u < 25; ++u) acc[s][u] += bv;
    }
    // contraction: out[o,t,v] = sum_u attn[o,u,v] * x3[o,t,u]; two o-halves of 16
    #pragma unroll
    for (int half = 0; half < 2; ++half) {
        __syncthreads();
        // attn[n, o0+half*16 + ol, u, v] -> smem[ol*700 + u*28 + v] (16B-aligned rows)
        for (int i = threadIdx.x; i < 16 * VV; i += 256) {
            int ol = i / VV, uv = i % VV;
            int u = uv / V_, v = uv % V_;
            smem[ol * 700 + u * 28 + v] =
                attn[((size_t)n * CO + o0 + half * 16 + ol) * VV + uv];
        }
        __syncthreads();
        #pragma unroll
        for (int si = 0; si < 2; ++si) {
            const int s  = half * 2 + si;
            const int ol = oo + si * 8;
            float oacc[25];
            #pragma unroll
            for (int v = 0; v < 25; ++v) oacc[v] = 0.f;
            #pragma unroll
            for (int u = 0; u < 25; ++u) {
                float a = acc[s][u];
                #pragma unroll
                for (int v = 0; v < 25; ++v) oacc[v] += smem[ol * 700 + u * 28 + v] * a;
            }
            float* op = out + ((size_t)(n * CO + o0 + oo + s * 8) * T_ + t0 + tloc) * V_;
            #pragma unroll
            for (int v = 0; v < 25; ++v) op[v] = oacc[v];
        }
    }
}

extern "C" void kernel_launch(void* const* d_in, const int* in_sizes, int n_in,
                              void* d_out, int out_size, void* d_ws, size_t ws_size,
                              hipStream_t stream) {
    const float* x  = (const float*)d_in[0];
    const float* A  = (const float*)d_in[1];
    const float* w1 = (const float*)d_in[2];
    const float* b1 = (const float*)d_in[3];
    const float* w2 = (const float*)d_in[4];
    const float* b2 = (const float*)d_in[5];
    const float* w3 = (const float*)d_in[6];
    const float* b3 = (const float*)d_in[7];
    const float* w4 = (const float*)d_in[8];
    const float* b4 = (const float*)d_in[9];
    const int* alpha_p = (const int*)d_in[11];
    float* out = (float*)d_out;

    float* ws   = (float*)d_ws;
    float* xm   = ws;                 // 409600
    float* x1   = ws + 409600;        // 51200
    float* x2   = ws + 460800;        // 51200
    float* attn = ws + 512000;        // 10240000

    k_mean<<<(N_ * CI * V_ + 255) / 256, 256, 0, stream>>>(x, xm);
    k_x1x2<<<N_, 256, 0, stream>>>(xm, w1, b1, w2, b2, x1, x2);
    k_attn<<<dim3(N_, 4), 256, 0, stream>>>(x1, x2, w4, b4, A, alpha_p, attn);
    k_gemm_contract<<<dim3(N_, 8, 2), 256, 0, stream>>>(x, w3, b3, attn, out);
}

// Round 2
// 543.308 us; speedup vs baseline: 1.9516x; 1.9516x over previous
//
#include <hip/hip_runtime.h>

#define N_  64
#define CI  256
#define CO  256
#define CR  32
#define T_  64
#define V_  25
#define TV  (T_*V_)   // 1600
#define VV  (V_*V_)   // 625

typedef __attribute__((ext_vector_type(8))) short bshort8;
typedef __attribute__((ext_vector_type(4))) short bshort4;
typedef __attribute__((ext_vector_type(4))) float f32x4;

__device__ inline unsigned short f2bf(float f) {
    unsigned int u = __float_as_uint(f);
    return (unsigned short)((u + 0x7FFFu + ((u >> 16) & 1u)) >> 16);
}
__device__ inline float bf2f(unsigned short s) {
    return __uint_as_float(((unsigned int)s) << 16);
}

// ---------------- K0: w3 -> bf16 ----------------
__global__ __launch_bounds__(256) void k_cvt_w3(const float* __restrict__ w3,
                                                unsigned short* __restrict__ w3b) {
    int idx = (blockIdx.x * 256 + threadIdx.x) * 4;
    float4 v = *(const float4*)(w3 + idx);
    bshort4 pk;
    pk[0] = (short)f2bf(v.x); pk[1] = (short)f2bf(v.y);
    pk[2] = (short)f2bf(v.z); pk[3] = (short)f2bf(v.w);
    *(bshort4*)(w3b + idx) = pk;
}

// ---------------- K1: xm[n,c,v] = mean_t x[n,c,t,v] ----------------
__global__ __launch_bounds__(256) void k_mean(const float* __restrict__ x,
                                              float* __restrict__ xm) {
    int idx = blockIdx.x * 256 + threadIdx.x;
    if (idx >= N_ * CI * V_) return;
    int v  = idx % V_;
    int nc = idx / V_;
    const float* p = x + (size_t)nc * TV + v;
    float s = 0.f;
    for (int t = 0; t < T_; ++t) s += p[t * V_];
    xm[idx] = s * (1.f / T_);
}

// ---------------- K1b: x[n,c,j] -> xT_bf[n,j,c] (transpose + bf16) ----------------
__global__ __launch_bounds__(256) void k_xpose(const float* __restrict__ x,
                                               unsigned short* __restrict__ xT) {
    int n  = blockIdx.x;
    int c0 = blockIdx.y * 64;
    int j0 = blockIdx.z * 64;
    __shared__ float L[64 * 65];     // [j][c] with pad
    int tid = threadIdx.x;
    #pragma unroll
    for (int p = 0; p < 4; ++p) {
        int cc = p * 16 + (tid >> 4);
        int f4 = tid & 15;
        float4 v = *(const float4*)(x + (size_t)n * CI * TV + (size_t)(c0 + cc) * TV + j0 + f4 * 4);
        L[(f4 * 4 + 0) * 65 + cc] = v.x;
        L[(f4 * 4 + 1) * 65 + cc] = v.y;
        L[(f4 * 4 + 2) * 65 + cc] = v.z;
        L[(f4 * 4 + 3) * 65 + cc] = v.w;
    }
    __syncthreads();
    int jl = tid >> 2, seg = tid & 3;
    bshort8 o0v, o1v;
    #pragma unroll
    for (int q = 0; q < 8; ++q) o0v[q] = (short)f2bf(L[jl * 65 + seg * 16 + q]);
    #pragma unroll
    for (int q = 0; q < 8; ++q) o1v[q] = (short)f2bf(L[jl * 65 + seg * 16 + 8 + q]);
    unsigned short* dst = xT + (size_t)n * (TV * CI) + (size_t)(j0 + jl) * CI + c0 + seg * 16;
    *(bshort8*)dst = o0v;
    *(bshort8*)(dst + 8) = o1v;
}

// ---------------- K2: x1/x2 = w1/w2 @ xm + b ----------------
__global__ __launch_bounds__(256) void k_x1x2(const float* __restrict__ xm,
                                              const float* __restrict__ w1,
                                              const float* __restrict__ b1,
                                              const float* __restrict__ w2,
                                              const float* __restrict__ b2,
                                              float* __restrict__ x1,
                                              float* __restrict__ x2) {
    int n = blockIdx.x;
    __shared__ float s_xm[CI * V_];
    const float4* src = (const float4*)(xm + (size_t)n * CI * V_);
    for (int i = threadIdx.x; i < CI * V_ / 4; i += 256) ((float4*)s_xm)[i] = src[i];
    __syncthreads();
    for (int idx = threadIdx.x; idx < CR * V_; idx += 256) {
        int r = idx / V_, v = idx % V_;
        float a1 = 0.f, a2 = 0.f;
        for (int c = 0; c < CI; ++c) {
            float xv = s_xm[c * V_ + v];
            a1 += w1[r * CI + c] * xv;
            a2 += w2[r * CI + c] * xv;
        }
        x1[n * CR * V_ + idx] = a1 + b1[r];
        x2[n * CR * V_ + idx] = a2 + b2[r];
    }
}

// ---------------- K3: attn[n,o,u,v] (fp32) ----------------
#define AFF_S 33
__global__ __launch_bounds__(256) void k_attn(const float* __restrict__ x1,
                                              const float* __restrict__ x2,
                                              const float* __restrict__ w4,
                                              const float* __restrict__ b4,
                                              const float* __restrict__ A,
                                              const int* __restrict__ alpha_p,
                                              float* __restrict__ attn) {
    int n  = blockIdx.x;
    int o0 = blockIdx.y * 64;
    __shared__ float s_x1[CR * V_];
    __shared__ float s_x2[CR * V_];
    __shared__ float s_aff[VV * AFF_S];
    __shared__ float s_w4[64 * CR];
    __shared__ float s_A[VV];
    float alpha = (float)alpha_p[0];
    for (int i = threadIdx.x; i < CR * V_; i += 256) {
        s_x1[i] = x1[n * CR * V_ + i];
        s_x2[i] = x2[n * CR * V_ + i];
    }
    for (int i = threadIdx.x; i < 64 * CR; i += 256) s_w4[i] = w4[o0 * CR + i];
    for (int i = threadIdx.x; i < VV; i += 256) s_A[i] = A[i];
    __syncthreads();
    for (int i = threadIdx.x; i < VV * CR; i += 256) {
        int r = i % CR;
        int uv = i / CR;
        int u = uv / V_, v = uv % V_;
        s_aff[uv * AFF_S + r] = tanhf(s_x1[r * V_ + u] - s_x2[r * V_ + v]);
    }
    __syncthreads();
    for (int base = 0; base < VV; base += 256) {
        int uv = base + threadIdx.x;
        if (uv >= VV) break;
        float av[CR];
        #pragma unroll
        for (int r = 0; r < CR; ++r) av[r] = s_aff[uv * AFF_S + r];
        float Auv = s_A[uv];
        for (int oo = 0; oo < 64; ++oo) {
            float acc = b4[o0 + oo];
            #pragma unroll
            for (int r = 0; r < CR; ++r) acc += s_w4[oo * CR + r] * av[r];
            attn[((size_t)n * CO + o0 + oo) * VV + uv] = acc * alpha + Auv;
        }
    }
}

// ---------------- K4: MFMA GEMM  x3_bf[n,o,j] = bf16(w3 @ x + b3) ----------------
// tile 64(o) x 64(j), K=256 staged once; XOR-swizzled LDS (16B granule), exactly 64 KB
__global__ __launch_bounds__(256) void k_gemm1(const unsigned short* __restrict__ xT,
                                               const unsigned short* __restrict__ w3b,
                                               const float* __restrict__ b3,
                                               unsigned short* __restrict__ x3) {
    int n = blockIdx.x, o0 = blockIdx.y * 64, j0 = blockIdx.z * 64;
    __shared__ unsigned short sA[64 * 256];
    __shared__ unsigned short sB[64 * 256];
    int tid  = threadIdx.x;
    int lane = tid & 63, wave = tid >> 6;
    const unsigned short* gA = w3b + o0 * CI;
    const unsigned short* gB = xT + (size_t)n * (TV * CI) + (size_t)j0 * CI;
    #pragma unroll
    for (int pp = 0; pp < 8; ++pp) {
        int task = pp * 256 + tid;
        int row = task >> 5, part = task & 31;
        int phys = part ^ (row & 7);
        bshort8 va = *(const bshort8*)(gA + row * 256 + part * 8);
        bshort8 vb = *(const bshort8*)(gB + row * 256 + part * 8);
        *(bshort8*)(&sA[row * 256 + phys * 8]) = va;
        *(bshort8*)(&sB[row * 256 + phys * 8]) = vb;
    }
    __syncthreads();
    int wo = wave >> 1, wj = wave & 1;
    int quad = lane >> 4, c16 = lane & 15;
    f32x4 acc00 = {0,0,0,0}, acc01 = {0,0,0,0}, acc10 = {0,0,0,0}, acc11 = {0,0,0,0};
    int rA0 = wo * 32 + c16, rA1 = rA0 + 16;
    int rB0 = wj * 32 + c16, rB1 = rB0 + 16;
    #pragma unroll
    for (int ks = 0; ks < 8; ++ks) {
        int cidx = ks * 4 + quad;
        bshort8 a0 = *(const bshort8*)(&sA[rA0 * 256 + ((cidx ^ (rA0 & 7)) << 3)]);
        bshort8 a1 = *(const bshort8*)(&sA[rA1 * 256 + ((cidx ^ (rA1 & 7)) << 3)]);
        bshort8 b0 = *(const bshort8*)(&sB[rB0 * 256 + ((cidx ^ (rB0 & 7)) << 3)]);
        bshort8 b1 = *(const bshort8*)(&sB[rB1 * 256 + ((cidx ^ (rB1 & 7)) << 3)]);
        acc00 = __builtin_amdgcn_mfma_f32_16x16x32_bf16(a0, b0, acc00, 0, 0, 0);
        acc01 = __builtin_amdgcn_mfma_f32_16x16x32_bf16(a0, b1, acc01, 0, 0, 0);
        acc10 = __builtin_amdgcn_mfma_f32_16x16x32_bf16(a1, b0, acc10, 0, 0, 0);
        acc11 = __builtin_amdgcn_mfma_f32_16x16x32_bf16(a1, b1, acc11, 0, 0, 0);
    }
    __syncthreads();
    // epilogue via LDS (stride 72 shorts = 144 B, 16B-aligned rows)
    unsigned short* eS = sA;
    #pragma unroll
    for (int mt = 0; mt < 2; ++mt) {
        #pragma unroll
        for (int nt = 0; nt < 2; ++nt) {
            const f32x4 accv = mt == 0 ? (nt == 0 ? acc00 : acc01)
                                       : (nt == 0 ? acc10 : acc11);
            int m  = wo * 32 + mt * 16 + quad * 4;
            int jc = wj * 32 + nt * 16 + c16;
            #pragma unroll
            for (int r = 0; r < 4; ++r) {
                float vv = accv[r] + b3[o0 + m + r];
                eS[(m + r) * 72 + jc] = f2bf(vv);
            }
        }
    }
    __syncthreads();
    int row = tid >> 2, seg = tid & 3;
    bshort8 v0 = *(const bshort8*)(&eS[row * 72 + seg * 16]);
    bshort8 v1 = *(const bshort8*)(&eS[row * 72 + seg * 16 + 8]);
    unsigned short* gp = x3 + (size_t)n * (CO * TV) + (size_t)(o0 + row) * TV + j0 + seg * 16;
    *(bshort8*)gp = v0;
    *(bshort8*)(gp + 8) = v1;
}

// ---------------- K5: out[n,o,t,v] = sum_u attn[n,o,u,v] * x3[n,o,t,u] ----------------
// x3 row register-cached per thread; attn via wave-uniform scalar loads (s_load)
__global__ __launch_bounds__(256) void k_contract(const unsigned short* __restrict__ x3,
                                                  const float* __restrict__ attn,
                                                  float* __restrict__ out) {
    int no = blockIdx.x;             // n*CO + o
    __shared__ float sXf[TV];
    __shared__ float sOut[TV];
    int tid = threadIdx.x;
    const unsigned short* xp = x3 + (size_t)no * TV;
    if (tid < 200) {
        bshort8 v = *(const bshort8*)(xp + tid * 8);
        #pragma unroll
        for (int k = 0; k < 8; ++k)
            sXf[tid * 8 + k] = bf2f((unsigned short)v[k]);
    }
    __syncthreads();
    int t  = tid & 63;
    int vg = __builtin_amdgcn_readfirstlane(tid >> 6);   // wave-uniform -> s_loads
    float xr[25];
    #pragma unroll
    for (int u = 0; u < 25; ++u) xr[u] = sXf[t * 25 + u];
    const float* ap = attn + (size_t)no * VV;
    #pragma unroll
    for (int i = 0; i < 7; ++i) {
        int v = vg * 7 + i;
        if (v < 25) {
            float acc = 0.f;
            #pragma unroll
            for (int u = 0; u < 25; ++u) acc += xr[u] * ap[u * 25 + v];
            sOut[t * 25 + v] = acc;
        }
    }
    __syncthreads();
    float* op = out + (size_t)no * TV;
    #pragma unroll
    for (int k2 = 0; k2 < 2; ++k2) {
        int idx = k2 * 256 + tid;
        if (idx < 400)
            *(float4*)(op + idx * 4) = *(const float4*)(&sOut[idx * 4]);
    }
}

extern "C" void kernel_launch(void* const* d_in, const int* in_sizes, int n_in,
                              void* d_out, int out_size, void* d_ws, size_t ws_size,
                              hipStream_t stream) {
    const float* x  = (const float*)d_in[0];
    const float* A  = (const float*)d_in[1];
    const float* w1 = (const float*)d_in[2];
    const float* b1 = (const float*)d_in[3];
    const float* w2 = (const float*)d_in[4];
    const float* b2 = (const float*)d_in[5];
    const float* w3 = (const float*)d_in[6];
    const float* b3 = (const float*)d_in[7];
    const float* w4 = (const float*)d_in[8];
    const float* b4 = (const float*)d_in[9];
    const int* alpha_p = (const int*)d_in[11];
    float* out = (float*)d_out;

    float* ws   = (float*)d_ws;
    float* xm   = ws;                       // 409600 f
    float* x1   = ws + 409600;              // 51200 f
    float* x2   = ws + 460800;              // 51200 f
    float* attn = ws + 512000;              // 10240000 f
    unsigned short* w3b = (unsigned short*)(ws + 10752000);   // 65536 us
    unsigned short* xT  = w3b + 65536;                        // 26214400 us
    unsigned short* x3b = xT + 26214400;                      // 26214400 us

    k_cvt_w3<<<64, 256, 0, stream>>>(w3, w3b);
    k_mean<<<(N_ * CI * V_ + 255) / 256, 256, 0, stream>>>(x, xm);
    k_xpose<<<dim3(N_, 4, 25), 256, 0, stream>>>(x, xT);
    k_x1x2<<<N_, 256, 0, stream>>>(xm, w1, b1, w2, b2, x1, x2);
    k_attn<<<dim3(N_, 4), 256, 0, stream>>>(x1, x2, w4, b4, A, alpha_p, attn);
    k_gemm1<<<dim3(N_, 4, 25), 256, 0, stream>>>(xT, w3b, b3, x3b);
    k_contract<<<N_ * CO, 256, 0, stream>>>(x3b, attn, out);
}

// Round 3
// 407.956 us; speedup vs baseline: 2.5991x; 1.3318x over previous
//
#include <hip/hip_runtime.h>

#define N_  64
#define CI  256
#define CO  256
#define CR  32
#define T_  64
#define V_  25
#define TV  (T_*V_)   // 1600
#define VV  (V_*V_)   // 625
#define ATS 640       // attnT per-(n,o) stride in shorts (625 used, pad to 16B-aligned)

typedef __attribute__((ext_vector_type(8))) short bshort8;
typedef __attribute__((ext_vector_type(4))) short bshort4;
typedef __attribute__((ext_vector_type(4))) float f32x4;

__device__ inline unsigned short f2bf(float f) {
    unsigned int u = __float_as_uint(f);
    return (unsigned short)((u + 0x7FFFu + ((u >> 16) & 1u)) >> 16);
}

// ---------------- K0: w3 -> bf16 in MFMA A-fragment order ----------------
// w3f[((ot*8+ks)*64+lane)*8+i] = w3[ot*16+(lane&15)][ks*32+(lane>>4)*8+i]
__global__ __launch_bounds__(256) void k_cvt_w3f(const float* __restrict__ w3,
                                                 unsigned short* __restrict__ w3f) {
    int f = blockIdx.x * 256 + threadIdx.x;        // 0..8191
    int lane = f & 63;
    int ks = (f >> 6) & 7;
    int ot = f >> 9;
    const float* src = w3 + (size_t)(ot * 16 + (lane & 15)) * CI + ks * 32 + (lane >> 4) * 8;
    bshort8 v;
    #pragma unroll
    for (int i = 0; i < 8; ++i) v[i] = (short)f2bf(src[i]);
    *(bshort8*)(w3f + (size_t)f * 8) = v;
}

// ---------------- K1: xm[n,c,v] = mean_t x[n,c,t,v] ----------------
__global__ __launch_bounds__(256) void k_mean(const float* __restrict__ x,
                                              float* __restrict__ xm) {
    int idx = blockIdx.x * 256 + threadIdx.x;
    if (idx >= N_ * CI * V_) return;
    int v  = idx % V_;
    int nc = idx / V_;
    const float* p = x + (size_t)nc * TV + v;
    float s = 0.f;
    for (int t = 0; t < T_; ++t) s += p[t * V_];
    xm[idx] = s * (1.f / T_);
}

// ---------------- K1b: x[n,c,j] -> xT_bf[n,j,c] ----------------
__global__ __launch_bounds__(256) void k_xpose(const float* __restrict__ x,
                                               unsigned short* __restrict__ xT) {
    int n  = blockIdx.x;
    int c0 = blockIdx.y * 64;
    int j0 = blockIdx.z * 64;
    __shared__ float L[64 * 65];
    int tid = threadIdx.x;
    #pragma unroll
    for (int p = 0; p < 4; ++p) {
        int cc = p * 16 + (tid >> 4);
        int f4 = tid & 15;
        float4 v = *(const float4*)(x + (size_t)n * CI * TV + (size_t)(c0 + cc) * TV + j0 + f4 * 4);
        L[(f4 * 4 + 0) * 65 + cc] = v.x;
        L[(f4 * 4 + 1) * 65 + cc] = v.y;
        L[(f4 * 4 + 2) * 65 + cc] = v.z;
        L[(f4 * 4 + 3) * 65 + cc] = v.w;
    }
    __syncthreads();
    int jl = tid >> 2, seg = tid & 3;
    bshort8 o0v, o1v;
    #pragma unroll
    for (int q = 0; q < 8; ++q) o0v[q] = (short)f2bf(L[jl * 65 + seg * 16 + q]);
    #pragma unroll
    for (int q = 0; q < 8; ++q) o1v[q] = (short)f2bf(L[jl * 65 + seg * 16 + 8 + q]);
    unsigned short* dst = xT + (size_t)n * (TV * CI) + (size_t)(j0 + jl) * CI + c0 + seg * 16;
    *(bshort8*)dst = o0v;
    *(bshort8*)(dst + 8) = o1v;
}

// ---------------- K2: x1/x2 = w1/w2 @ xm + b ----------------
__global__ __launch_bounds__(256) void k_x1x2(const float* __restrict__ xm,
                                              const float* __restrict__ w1,
                                              const float* __restrict__ b1,
                                              const float* __restrict__ w2,
                                              const float* __restrict__ b2,
                                              float* __restrict__ x1,
                                              float* __restrict__ x2) {
    int n = blockIdx.x;
    __shared__ float s_xm[CI * V_];
    const float4* src = (const float4*)(xm + (size_t)n * CI * V_);
    for (int i = threadIdx.x; i < CI * V_ / 4; i += 256) ((float4*)s_xm)[i] = src[i];
    __syncthreads();
    for (int idx = threadIdx.x; idx < CR * V_; idx += 256) {
        int r = idx / V_, v = idx % V_;
        float a1 = 0.f, a2 = 0.f;
        for (int c = 0; c < CI; ++c) {
            float xv = s_xm[c * V_ + v];
            a1 += w1[r * CI + c] * xv;
            a2 += w2[r * CI + c] * xv;
        }
        x1[n * CR * V_ + idx] = a1 + b1[r];
        x2[n * CR * V_ + idx] = a2 + b2[r];
    }
}

// ---------------- K3: attnT bf16 [n][o][v][u-packed25, stride ATS per (n,o)] ----------------
// attnT[v][u] = (sum_r w4[o,r]*tanh(x1[r,u]-x2[r,v]) + b4[o]) * alpha + A[u,v]
__global__ __launch_bounds__(256) void k_attn(const float* __restrict__ x1,
                                              const float* __restrict__ x2,
                                              const float* __restrict__ w4,
                                              const float* __restrict__ b4,
                                              const float* __restrict__ A,
                                              const int* __restrict__ alpha_p,
                                              unsigned short* __restrict__ attnT) {
    int n  = blockIdx.x;
    int o0 = blockIdx.y * 64;
    __shared__ float s_x1[CR * V_];
    __shared__ float s_x2[CR * V_];
    __shared__ float s_aff[VV * 33];
    __shared__ float s_A[VV];
    __shared__ unsigned short sT[16 * ATS];
    int tid = threadIdx.x;
    float alpha = (float)alpha_p[0];
    for (int i = tid; i < CR * V_; i += 256) {
        s_x1[i] = x1[n * CR * V_ + i];
        s_x2[i] = x2[n * CR * V_ + i];
    }
    for (int i = tid; i < VV; i += 256) s_A[i] = A[i];
    __syncthreads();
    // s_aff[(v*25+u)][r] = tanh(x1[r,u] - x2[r,v])
    for (int i = tid; i < VV * CR; i += 256) {
        int uv = i / CR, r = i % CR;
        int u = uv % V_, v = uv / V_;
        s_aff[uv * 33 + r] = tanhf(s_x1[r * V_ + u] - s_x2[r * V_ + v]);
    }
    __syncthreads();
    for (int oc = 0; oc < 4; ++oc) {
        for (int pass = 0; pass < 3; ++pass) {
            int uv = pass * 256 + tid;
            if (uv < VV) {
                int u = uv % V_, v = uv / V_;
                float Auv = s_A[u * V_ + v];
                float av[CR];
                #pragma unroll
                for (int r = 0; r < CR; ++r) av[r] = s_aff[uv * 33 + r];
                #pragma unroll
                for (int ol = 0; ol < 16; ++ol) {
                    int o = o0 + oc * 16 + ol;
                    const float* wr = w4 + (size_t)o * CR;   // wave-uniform -> s_loads
                    float acc = b4[o];
                    #pragma unroll
                    for (int r = 0; r < CR; ++r) acc += wr[r] * av[r];
                    sT[ol * ATS + uv] = f2bf(acc * alpha + Auv);
                }
            }
        }
        __syncthreads();
        // coalesced store: 16 rows x 640 shorts = 1280 bshort8
        #pragma unroll
        for (int i = 0; i < 5; ++i) {
            int task = i * 256 + tid;
            int ol = task / 80, seg = task % 80;
            bshort8 vv = *(const bshort8*)&sT[ol * ATS + seg * 8];
            *(bshort8*)(attnT + (size_t)(n * CO + o0 + oc * 16 + ol) * ATS + seg * 8) = vv;
        }
        __syncthreads();
    }
}

// ---------------- K4: MFMA GEMM full-o: x3_bf[n,o,j] = bf16(w3 @ x + b3) ----------------
// block = (n, j-tile 64); o = 256; xT read ONCE; A-frags from fragment-ordered w3f (L2)
__global__ __launch_bounds__(256) void k_gemm1(const unsigned short* __restrict__ xT,
                                               const unsigned short* __restrict__ w3f,
                                               const float* __restrict__ b3,
                                               unsigned short* __restrict__ x3) {
    int n = blockIdx.x, j0 = blockIdx.y * 64;
    __shared__ unsigned short sB[64 * 256];
    int tid  = threadIdx.x;
    int lane = tid & 63, wave = tid >> 6;
    const unsigned short* gB = xT + (size_t)n * (TV * CI) + (size_t)j0 * CI;
    #pragma unroll
    for (int pp = 0; pp < 8; ++pp) {
        int task = pp * 256 + tid;
        int row = task >> 5, part = task & 31;
        int phys = part ^ (row & 7);
        *(bshort8*)(&sB[row * 256 + phys * 8]) = *(const bshort8*)(gB + row * 256 + part * 8);
    }
    __syncthreads();
    int quad = lane >> 4, c16 = lane & 15;
    const bshort8* Af = (const bshort8*)w3f;
    f32x4 acc[4][4];
    #pragma unroll
    for (int mt = 0; mt < 4; ++mt)
        #pragma unroll
        for (int nt = 0; nt < 4; ++nt) acc[mt][nt] = (f32x4){0,0,0,0};
    #pragma unroll
    for (int ks = 0; ks < 8; ++ks) {
        bshort8 b[4], a[4];
        #pragma unroll
        for (int nt = 0; nt < 4; ++nt) {
            int rB = nt * 16 + c16;
            int cidx = ks * 4 + quad;
            b[nt] = *(const bshort8*)(&sB[rB * 256 + ((cidx ^ (rB & 7)) << 3)]);
        }
        #pragma unroll
        for (int mt = 0; mt < 4; ++mt)
            a[mt] = Af[(size_t)(((wave * 4 + mt) * 8 + ks) * 64) + lane];
        #pragma unroll
        for (int mt = 0; mt < 4; ++mt)
            #pragma unroll
            for (int nt = 0; nt < 4; ++nt)
                acc[mt][nt] = __builtin_amdgcn_mfma_f32_16x16x32_bf16(a[mt], b[nt], acc[mt][nt], 0, 0, 0);
    }
    __syncthreads();                      // sB free; alias as epilogue buffer
    unsigned short* eS = sB;              // 128 rows x stride 72 shorts
    #pragma unroll
    for (int pass = 0; pass < 2; ++pass) {
        if ((wave >> 1) == pass) {
            #pragma unroll
            for (int mt = 0; mt < 4; ++mt) {
                int o = wave * 64 + mt * 16 + quad * 4;
                float4 bv = *(const float4*)(b3 + o);
                int ol = (wave & 1) * 64 + mt * 16 + quad * 4;
                #pragma unroll
                for (int nt = 0; nt < 4; ++nt) {
                    int jc = nt * 16 + c16;
                    eS[(ol + 0) * 72 + jc] = f2bf(acc[mt][nt][0] + bv.x);
                    eS[(ol + 1) * 72 + jc] = f2bf(acc[mt][nt][1] + bv.y);
                    eS[(ol + 2) * 72 + jc] = f2bf(acc[mt][nt][2] + bv.z);
                    eS[(ol + 3) * 72 + jc] = f2bf(acc[mt][nt][3] + bv.w);
                }
            }
        }
        __syncthreads();
        #pragma unroll
        for (int i = 0; i < 4; ++i) {
            int task = i * 256 + tid;         // 1024
            int orow = task >> 3, seg = task & 7;
            bshort8 vv = *(const bshort8*)&eS[orow * 72 + seg * 8];
            *(bshort8*)(x3 + (size_t)(n * CO + pass * 128 + orow) * TV + j0 + seg * 8) = vv;
        }
        __syncthreads();
    }
}

// ---------------- K5: MFMA contraction: out[t,v] = sum_u x3[t,u] * attnT[v,u] ----------------
// block = 4 (n,o) pairs, one wave each; u padded to 32 (zeros in A and B pads)
__global__ __launch_bounds__(256) void k_contract(const unsigned short* __restrict__ x3,
                                                  const unsigned short* __restrict__ attnT,
                                                  float* __restrict__ out) {
    int no0 = blockIdx.x * 4;
    __shared__ __align__(16) unsigned char smem[28672];
    unsigned short* sA = (unsigned short*)smem;            // 4 x [64][32]
    unsigned short* sB = (unsigned short*)(smem + 16384);  // 4 x [32][32]
    float*          sO = (float*)smem;                     // 4 x [64][28]
    int tid = threadIdx.x;
    // zero u-pads
    #pragma unroll
    for (int i = 0; i < 7; ++i) {
        int task = i * 256 + tid;              // 4*64*7 = 1792
        if (task < 1792) {
            int p = task / 448, rem = task % 448;
            sA[p * 2048 + (rem / 7) * 32 + 25 + rem % 7] = 0;
        }
    }
    {
        int task = tid;                         // 4*25*7 = 700
        for (int i = 0; i < 3; ++i, task += 256)
            if (task < 700) {
                int p = task / 175, rem = task % 175;
                sB[p * 1024 + (rem / 7) * 32 + 25 + rem % 7] = 0;
            }
    }
    // stage x3 (scatter to u-stride 32)
    #pragma unroll
    for (int i = 0; i < 4; ++i) {
        int task = i * 256 + tid;              // 800
        if (task < 800) {
            int p = task / 200, e8 = task % 200;
            bshort8 vv = *(const bshort8*)(x3 + (size_t)(no0 + p) * TV + e8 * 8);
            #pragma unroll
            for (int k = 0; k < 8; ++k) {
                int j = e8 * 8 + k;
                int t = j / 25, u = j % 25;
                sA[p * 2048 + t * 32 + u] = (unsigned short)vv[k];
            }
        }
    }
    // stage attnT (scatter to u-stride 32)
    #pragma unroll
    for (int i = 0; i < 2; ++i) {
        int task = i * 256 + tid;              // 4*79 = 316
        if (task < 316) {
            int p = task / 79, e8 = task % 79;
            bshort8 vv = *(const bshort8*)(attnT + (size_t)(no0 + p) * ATS + e8 * 8);
            #pragma unroll
            for (int k = 0; k < 8; ++k) {
                int idx = e8 * 8 + k;
                if (idx < VV) {
                    int v = idx / 25, u = idx % 25;
                    sB[p * 1024 + v * 32 + u] = (unsigned short)vv[k];
                }
            }
        }
    }
    __syncthreads();
    int p = tid >> 6, lane = tid & 63;
    int quad = lane >> 4, c16 = lane & 15;
    const unsigned short* pA = sA + p * 2048;
    const unsigned short* pB = sB + p * 1024;
    bshort8 a[4], b[2];
    #pragma unroll
    for (int mt = 0; mt < 4; ++mt) a[mt] = *(const bshort8*)&pA[(mt * 16 + c16) * 32 + quad * 8];
    #pragma unroll
    for (int nt = 0; nt < 2; ++nt) b[nt] = *(const bshort8*)&pB[(nt * 16 + c16) * 32 + quad * 8];
    f32x4 acc[4][2];
    #pragma unroll
    for (int mt = 0; mt < 4; ++mt)
        #pragma unroll
        for (int nt = 0; nt < 2; ++nt)
            acc[mt][nt] = __builtin_amdgcn_mfma_f32_16x16x32_bf16(a[mt], b[nt], (f32x4){0,0,0,0}, 0, 0, 0);
    __syncthreads();     // frag reads done; alias sO
    float* pO = sO + p * 1792;
    #pragma unroll
    for (int mt = 0; mt < 4; ++mt)
        #pragma unroll
        for (int nt = 0; nt < 2; ++nt) {
            int v = nt * 16 + c16;
            if (v < V_) {
                #pragma unroll
                for (int r = 0; r < 4; ++r) {
                    int t = mt * 16 + quad * 4 + r;
                    pO[t * 28 + v] = acc[mt][nt][r];
                }
            }
        }
    __syncthreads();
    #pragma unroll
    for (int i = 0; i < 25; ++i) {
        int idx = i * 256 + tid;               // 6400
        int p2 = idx / TV, rem = idx % TV;
        int t = rem / 25, v = rem % 25;
        out[(size_t)(no0 + p2) * TV + rem] = sO[p2 * 1792 + t * 28 + v];
    }
}

extern "C" void kernel_launch(void* const* d_in, const int* in_sizes, int n_in,
                              void* d_out, int out_size, void* d_ws, size_t ws_size,
                              hipStream_t stream) {
    const float* x  = (const float*)d_in[0];
    const float* A  = (const float*)d_in[1];
    const float* w1 = (const float*)d_in[2];
    const float* b1 = (const float*)d_in[3];
    const float* w2 = (const float*)d_in[4];
    const float* b2 = (const float*)d_in[5];
    const float* w3 = (const float*)d_in[6];
    const float* b3 = (const float*)d_in[7];
    const float* w4 = (const float*)d_in[8];
    const float* b4 = (const float*)d_in[9];
    const int* alpha_p = (const int*)d_in[11];
    float* out = (float*)d_out;

    float* ws = (float*)d_ws;
    float* xm = ws;                                            // 409600 f
    float* x1 = ws + 409600;                                   // 51200 f
    float* x2 = ws + 460800;                                   // 51200 f
    unsigned short* attnT = (unsigned short*)(ws + 512000);    // 16384*640 us
    unsigned short* w3f   = attnT + (size_t)16384 * ATS;       // 65536 us
    unsigned short* xT    = w3f + 65536;                       // 26214400 us
    unsigned short* x3    = xT + (size_t)26214400;             // 26214400 us

    k_cvt_w3f<<<32, 256, 0, stream>>>(w3, w3f);
    k_xpose<<<dim3(N_, 4, 25), 256, 0, stream>>>(x, xT);
    k_mean<<<(N_ * CI * V_ + 255) / 256, 256, 0, stream>>>(x, xm);
    k_x1x2<<<N_, 256, 0, stream>>>(xm, w1, b1, w2, b2, x1, x2);
    k_attn<<<dim3(N_, 4), 256, 0, stream>>>(x1, x2, w4, b4, A, alpha_p, attnT);
    k_gemm1<<<dim3(N_, 25), 256, 0, stream>>>(xT, w3f, b3, x3);
    k_contract<<<4096, 256, 0, stream>>>(x3, attnT, out);
}